// Round 16
// baseline (194.829 us; speedup 1.0000x reference)
//
#include <hip/hip_runtime.h>
#include <math.h>

#define ACT_RELU 0
#define ACT_LSM  1
#define BSH 8        // bucket = 256 consecutive dst nodes
#define MAXNB 512    // max buckets supported by the scan / LDS hist
#define MPAD 80      // meanL row pad (ushorts)

typedef __attribute__((ext_vector_type(8))) short bf16x8;   // 8 bf16 (4 VGPRs)
typedef __attribute__((ext_vector_type(4))) float f32x4;

// bf16 helpers (OCP bf16 = top 16 bits of f32; RNE pack)
__device__ __forceinline__ unsigned f2bf(float f) {
  unsigned u = __float_as_uint(f);
  u += 0x7fffu + ((u >> 16) & 1u);
  return u >> 16;
}
__device__ __forceinline__ float bflo(unsigned u) { return __uint_as_float(u << 16); }
__device__ __forceinline__ float bfhi(unsigned u) { return __uint_as_float(u & 0xffff0000u); }

// ---------------- pre-pack ALL layer weights + zero bucket counts ----------------
__device__ __forceinline__ void prepw_one(const float* Wl, const float* Wr,
                                          unsigned short* Wb, int fi, int DOUT, int NT) {
  int k7 = fi & 7;
  int kb = (fi >> 3) & 3;
  int c16 = (fi >> 5) & 15;
  int rest = fi >> 9;
  int nt = rest % NT;
  int kb5 = rest / NT;
  int k = kb5 * 32 + kb * 8 + k7;
  int nn = nt * 16 + c16;
  float v = 0.f;
  if (nn < DOUT) v = (k < 64) ? Wl[k * DOUT + nn] : Wr[(k - 64) * DOUT + nn];
  Wb[fi] = (unsigned short)f2bf(v);
}

__global__ void k_prepw3(const float* __restrict__ Wl0, const float* __restrict__ Wr0,
                         unsigned short* __restrict__ Wb0,
                         const float* __restrict__ Wl1, const float* __restrict__ Wr1,
                         unsigned short* __restrict__ Wb1,
                         const float* __restrict__ Wl2, const float* __restrict__ Wr2,
                         unsigned short* __restrict__ Wb2,
                         int* __restrict__ bk_cnt) {
  int i = blockIdx.x * 256 + threadIdx.x;
  if (i < 8192) prepw_one(Wl0, Wr0, Wb0, i, 64, 4);
  else if (i < 16384) prepw_one(Wl1, Wr1, Wb1, i - 8192, 64, 4);
  else if (i < 22528) prepw_one(Wl2, Wr2, Wb2, i - 16384, 40, 3);
  if (i <= MAXNB) bk_cnt[i] = 0;  // fused zero of bucket counts
}

// ---------------- CSR build (bucketed, deterministic, atomic-light) ----------------
// Fused: grid-stride cast x->bf16 + per-4096-edge-chunk bucket histogram.
// Also stores per-(bucket,block) counts for the scan (no re-count in partition).
__global__ void __launch_bounds__(256) k_histB(const int* __restrict__ dst,
                                               const float* __restrict__ x,
                                               unsigned short* __restrict__ xb,
                                               int* __restrict__ bucket_cnt,
                                               int* __restrict__ bk_blk,  // [b*NBLK+blk]
                                               int E, int NB, int NBLK, int nx8) {
  __shared__ int cntL[MAXNB];
  int t = threadIdx.x;
  // ---- fused cast (grid-stride, independent of hist) ----
  for (int i = blockIdx.x * 256 + t; i < nx8; i += gridDim.x * 256) {
    const float4* p = (const float4*)(x + (size_t)i * 8);
    float4 a = p[0], b = p[1];
    uint4 w;
    w.x = f2bf(a.x) | (f2bf(a.y) << 16);
    w.y = f2bf(a.z) | (f2bf(a.w) << 16);
    w.z = f2bf(b.x) | (f2bf(b.y) << 16);
    w.w = f2bf(b.z) | (f2bf(b.w) << 16);
    *(uint4*)(xb + (size_t)i * 8) = w;
  }
  // ---- bucket histogram for this block's edge chunk ----
  for (int b = t; b < NB; b += 256) cntL[b] = 0;
  __syncthreads();
  int e0 = blockIdx.x * 4096;
  int e1 = min(e0 + 4096, E);
  for (int i = e0 + t; i < e1; i += 256) atomicAdd(&cntL[dst[i] >> BSH], 1);
  __syncthreads();
  for (int b = t; b < NB; b += 256) {
    int c = cntL[b];
    bk_blk[b * NBLK + blockIdx.x] = c;
    if (c) atomicAdd(&bucket_cnt[b], c);
  }
}

// Fused scans: every block redundantly computes the bucket-count prefix scan
// (512 values in LDS, cheap), block 0 publishes bucket_base; block b then scans
// its own per-(bucket,block) row to produce base_blk.
__global__ void __launch_bounds__(512) k_bscan12(const int* __restrict__ bucket_cnt,
                                                 const int* __restrict__ bk_blk,
                                                 int* __restrict__ bucket_base,
                                                 int* __restrict__ base_blk,
                                                 int NB, int NBLK) {
  __shared__ int sm[MAXNB];
  int b = blockIdx.x;   // one block per bucket
  int t = threadIdx.x;  // 512
  sm[t] = (t < NB) ? bucket_cnt[t] : 0;
  __syncthreads();
  for (int off = 1; off < MAXNB; off <<= 1) {
    int x = (t >= off) ? sm[t - off] : 0;
    __syncthreads();
    sm[t] += x;
    __syncthreads();
  }
  int my_base = (b == 0) ? 0 : sm[b - 1];
  if (b == 0) {
    int ex = (t == 0) ? 0 : sm[t - 1];
    if (t <= NB) bucket_base[t] = ex;  // requires NB <= 511
  }
  __syncthreads();
  // per-bucket per-block exclusive scan
  int v = (t < NBLK) ? bk_blk[b * NBLK + t] : 0;
  sm[t] = v;
  __syncthreads();
  for (int off = 1; off < MAXNB; off <<= 1) {
    int x = (t >= off) ? sm[t - off] : 0;
    __syncthreads();
    sm[t] += x;
    __syncthreads();
  }
  if (t < NBLK) base_blk[b * NBLK + t] = my_base + sm[t] - v;
}

// single-pass partition: per-block bases precomputed; tmp packed 4B (src<<8)|(dst&255)
__global__ void k_partition(const int* __restrict__ src, const int* __restrict__ dst,
                            const int* __restrict__ base_blk, unsigned* __restrict__ tmp,
                            int E, int NB, int NBLK) {
  __shared__ int curL[MAXNB];
  int t = threadIdx.x;
  for (int b = t; b < NB; b += 256) curL[b] = base_blk[b * NBLK + blockIdx.x];
  __syncthreads();
  int e0 = blockIdx.x * 4096;
  int e1 = min(e0 + 4096, E);
  for (int i = e0 + t; i < e1; i += 256) {
    int s = src[i], d = dst[i];
    int b = d >> BSH;
    int r = atomicAdd(&curL[b], 1);  // LDS atomic
    tmp[r] = ((unsigned)s << 8) | (unsigned)(d & 255);
  }
}

__global__ void __launch_bounds__(256) k_bmake(const unsigned* __restrict__ tmp,
                                               const int* __restrict__ bucket_base,
                                               int* __restrict__ row_ptr,
                                               int* __restrict__ edge_src,
                                               int N, int E, int NB) {
  __shared__ int cntL[256];
  __shared__ int scanL[256];
  int b = blockIdx.x;
  int t = threadIdx.x;
  int e0 = bucket_base[b], e1 = bucket_base[b + 1];
  cntL[t] = 0;
  __syncthreads();
  for (int i = e0 + t; i < e1; i += 256) atomicAdd(&cntL[tmp[i] & 255], 1);
  __syncthreads();
  int v = cntL[t];
  scanL[t] = v;
  __syncthreads();
  for (int off = 1; off < 256; off <<= 1) {
    int x = (t >= off) ? scanL[t - off] : 0;
    __syncthreads();
    scanL[t] += x;
    __syncthreads();
  }
  int exc = scanL[t] - v;
  int node = (b << BSH) + t;
  if (node < N) row_ptr[node] = e0 + exc;
  if (b == NB - 1 && t == 0) row_ptr[N] = E;
  __syncthreads();
  cntL[t] = e0 + exc;  // reuse as cursor
  __syncthreads();
  for (int i = e0 + t; i < e1; i += 256) {
    unsigned e = tmp[i];
    int p = atomicAdd(&cntL[e & 255], 1);  // LDS atomic
    edge_src[p] = (int)(e >> 8);
  }
}

// ---------------- fallback path (NB >= MAXNB or N >= 2^24 or NBLK > 512) ----------------
__global__ void k_zero(int* __restrict__ p, int n) {
  int i = blockIdx.x * 256 + threadIdx.x;
  if (i < n) p[i] = 0;
}

__global__ void k_hist(const int* __restrict__ dst, int* __restrict__ cnt, int E) {
  int i = blockIdx.x * blockDim.x + threadIdx.x;
  if (i < E) atomicAdd(&cnt[dst[i]], 1);
}

__global__ void k_scan_part(const int* __restrict__ cnt, int* __restrict__ bsum, int M) {
  __shared__ int sm[256];
  int t = threadIdx.x;
  int base = blockIdx.x * 2048 + t * 8;
  int s = 0;
#pragma unroll
  for (int j = 0; j < 8; ++j) { int i = base + j; if (i < M) s += cnt[i]; }
  sm[t] = s;
  __syncthreads();
  for (int off = 128; off > 0; off >>= 1) {
    if (t < off) sm[t] += sm[t + off];
    __syncthreads();
  }
  if (t == 0) bsum[blockIdx.x] = sm[0];
}

__global__ void k_scan_mid(const int* __restrict__ bsum, int* __restrict__ boff, int nb) {
  int l = threadIdx.x;
  int v = (l < nb) ? bsum[l] : 0;
  int inc = v;
  for (int off = 1; off < 64; off <<= 1) {
    int u = __shfl_up(inc, off);
    if (l >= off) inc += u;
  }
  if (l < nb) boff[l] = inc - v;
}

__global__ void k_scan_final(const int* __restrict__ cnt, const int* __restrict__ boff,
                             int* __restrict__ row_ptr, int* __restrict__ cursor, int M) {
  __shared__ int sm[256];
  int t = threadIdx.x;
  int base = blockIdx.x * 2048 + t * 8;
  int v[8];
  int s = 0;
#pragma unroll
  for (int j = 0; j < 8; ++j) { int i = base + j; v[j] = (i < M) ? cnt[i] : 0; s += v[j]; }
  sm[t] = s;
  __syncthreads();
  for (int off = 1; off < 256; off <<= 1) {
    int x = (t >= off) ? sm[t - off] : 0;
    __syncthreads();
    sm[t] += x;
    __syncthreads();
  }
  int run = boff[blockIdx.x] + sm[t] - s;
#pragma unroll
  for (int j = 0; j < 8; ++j) {
    int i = base + j;
    if (i < M) { row_ptr[i] = run; cursor[i] = run; }
    run += v[j];
  }
}

__global__ void k_fill(const int* __restrict__ src, const int* __restrict__ dst,
                       int* __restrict__ cursor, int* __restrict__ edge_src, int E) {
  int i = blockIdx.x * blockDim.x + threadIdx.x;
  if (i < E) {
    int d = dst[i];
    int p = atomicAdd(&cursor[d], 1);
    edge_src[p] = src[i];
  }
}

__global__ void __launch_bounds__(256) k_cast(const float* __restrict__ x,
                                              unsigned short* __restrict__ xb, int n) {
  int i = blockIdx.x * 256 + threadIdx.x;  // unit of 8 elements
  if (i * 8 < n) {
    const float4* p = (const float4*)(x + (size_t)i * 8);
    float4 a = p[0], b = p[1];
    uint4 w;
    w.x = f2bf(a.x) | (f2bf(a.y) << 16);
    w.y = f2bf(a.z) | (f2bf(a.w) << 16);
    w.z = f2bf(b.x) | (f2bf(b.y) << 16);
    w.w = f2bf(b.z) | (f2bf(b.w) << 16);
    *(uint4*)(xb + (size_t)i * 8) = w;
  }
}

// ---------------- fused SAGE layer: out = act([mean_agg(h), h] @ [Wl; Wr] + b) ----------------
// R13-proven structure: 4 waves/block, 16 rows/wave, wave-private meanL (no
// block barrier), W fragments from global (pre-packed), LDS 10.2KB.
// Phase A: gather-mean, 8 lanes/node, 8 edges in flight; guard-free full-batch
// fast path + guarded remainder. Phase B: MFMA K=128.
// mfma_f32_16x16x32_bf16: A row = lane&15, k = (lane>>4)*8+j; C/D col = lane&15,
// row = (lane>>4)*4 + reg  [verified R6-R15].
template <int DOUT, int ACT>
__global__ void __launch_bounds__(256) k_layer(const unsigned short* __restrict__ h,
                                               const int* __restrict__ row_ptr,
                                               const int* __restrict__ edge_src,
                                               const unsigned short* __restrict__ Wb,
                                               const float* __restrict__ bias,
                                               void* __restrict__ outv, int n) {
  constexpr int NT = (DOUT + 15) / 16;  // 4 (d=64) or 3 (d=40)
  __shared__ unsigned short meanL[4][16 * MPAD];
  int t = threadIdx.x;
  int w = t >> 6, lane = t & 63;
  int r0 = (blockIdx.x * 4 + w) * 16;  // wave's 16 rows
  int g = lane & 7;                    // dim-group of 8 bf16 (16B)
  int lb = lane & ~7;                  // first lane of node's group

  // ---- phase A: gather-mean, two batches of 8 nodes ----
  for (int half = 0; half < 2; ++half) {
    int node = half * 8 + (lane >> 3);
    int i = r0 + node;
    float a[8];
#pragma unroll
    for (int c = 0; c < 8; ++c) a[c] = 0.f;
    float scale = 0.f;
    if (i < n) {
      int rp0 = row_ptr[i], rp1 = row_ptr[i + 1];
      int deg = rp1 - rp0;
      scale = (deg > 0) ? (1.0f / (float)deg) : 0.f;
#define GLOAD(vv, ee, sv) \
      { int s_ = __shfl((sv), lb | (ee)); vv = *((const uint4*)(h + (size_t)s_ * 64) + g); }
#define ACCUM(vv)                                                       \
      { a[0] += bflo(vv.x); a[1] += bfhi(vv.x);                         \
        a[2] += bflo(vv.y); a[3] += bfhi(vv.y);                         \
        a[4] += bflo(vv.z); a[5] += bfhi(vv.z);                         \
        a[6] += bflo(vv.w); a[7] += bfhi(vv.w); }
      int base = 0;
      // guard-free full batches of 8 edges
      for (; base + 8 <= deg; base += 8) {
        int sv = edge_src[rp0 + base + g];
        uint4 v0, v1, v2, v3, v4, v5, v6, v7;
        GLOAD(v0, 0, sv) GLOAD(v1, 1, sv) GLOAD(v2, 2, sv) GLOAD(v3, 3, sv)
        GLOAD(v4, 4, sv) GLOAD(v5, 5, sv) GLOAD(v6, 6, sv) GLOAD(v7, 7, sv)
        ACCUM(v0) ACCUM(v1) ACCUM(v2) ACCUM(v3)
        ACCUM(v4) ACCUM(v5) ACCUM(v6) ACCUM(v7)
      }
      // guarded remainder (1..7 edges)
      if (base < deg) {
        int cnt = deg - base;
        int idx = rp0 + base + g;
        int sv = (idx < rp1) ? edge_src[idx] : 0;
        uint4 v0, v1, v2, v3, v4, v5, v6;
#define TLOAD(vv, ee) if ((ee) < cnt) GLOAD(vv, ee, sv)
#define TACC(vv, ee)  if ((ee) < cnt) ACCUM(vv)
        TLOAD(v0, 0) TLOAD(v1, 1) TLOAD(v2, 2) TLOAD(v3, 3)
        TLOAD(v4, 4) TLOAD(v5, 5) TLOAD(v6, 6)
        TACC(v0, 0) TACC(v1, 1) TACC(v2, 2) TACC(v3, 3)
        TACC(v4, 4) TACC(v5, 5) TACC(v6, 6)
#undef TLOAD
#undef TACC
      }
#undef GLOAD
#undef ACCUM
    }
    uint4 wv;
    wv.x = f2bf(a[0] * scale) | (f2bf(a[1] * scale) << 16);
    wv.y = f2bf(a[2] * scale) | (f2bf(a[3] * scale) << 16);
    wv.z = f2bf(a[4] * scale) | (f2bf(a[5] * scale) << 16);
    wv.w = f2bf(a[6] * scale) | (f2bf(a[7] * scale) << 16);
    *(uint4*)&meanL[w][node * MPAD + g * 8] = wv;
  }
  // meanL is wave-private: LDS fence only, no block barrier.
  __threadfence_block();

  // ---- phase B: MFMA ----
  int c = lane & 15;   // A row / C-D col
  int kb = lane >> 4;  // k-block of 8
  bf16x8 af[4];
  af[0] = *(const bf16x8*)&meanL[w][c * MPAD + kb * 8];        // mean, k 0..31
  af[1] = *(const bf16x8*)&meanL[w][c * MPAD + 32 + kb * 8];   // mean, k 32..63
  int row = r0 + c;
  if (row >= n) row = n - 1;  // clamp loads; stores guarded
  size_t rb = (size_t)row * 64 + kb * 8;
  af[2] = *(const bf16x8*)(h + rb);        // own row, k 0..31
  af[3] = *(const bf16x8*)(h + rb + 32);   // own row, k 32..63

  f32x4 acc[NT];
#pragma unroll
  for (int nt = 0; nt < NT; ++nt) acc[nt] = (f32x4){0.f, 0.f, 0.f, 0.f};
#pragma unroll
  for (int s = 0; s < 4; ++s) {
    bf16x8 bft[NT];  // load W frags per-s to cap register liveness
#pragma unroll
    for (int nt = 0; nt < NT; ++nt)
      bft[nt] = *(const bf16x8*)&Wb[(((s * NT + nt) * 16 + c) * 4 + kb) * 8];
#pragma unroll
    for (int nt = 0; nt < NT; ++nt)
      acc[nt] = __builtin_amdgcn_mfma_f32_16x16x32_bf16(af[s], bft[nt], acc[nt], 0, 0, 0);
  }

  int rbase = r0 + kb * 4;
  if (ACT == ACT_RELU) {
    unsigned short* out = (unsigned short*)outv;
#pragma unroll
    for (int nt = 0; nt < NT; ++nt) {
      float bval = bias[nt * 16 + c];
#pragma unroll
      for (int r = 0; r < 4; ++r) {
        int R = rbase + r;
        if (R < n) {
          float v = fmaxf(acc[nt][r] + bval, 0.f);
          out[(size_t)R * DOUT + nt * 16 + c] = (unsigned short)f2bf(v);
        }
      }
    }
  } else {
    float* out = (float*)outv;
    float bv[NT];
#pragma unroll
    for (int nt = 0; nt < NT; ++nt) bv[nt] = ((nt * 16 + c) < DOUT) ? bias[nt * 16 + c] : 0.f;
#pragma unroll
    for (int r = 0; r < 4; ++r) {
      int R = rbase + r;
      float v[NT];
      float m = -INFINITY;
#pragma unroll
      for (int nt = 0; nt < NT; ++nt) {
        bool valid = (nt * 16 + c) < DOUT;
        v[nt] = valid ? (acc[nt][r] + bv[nt]) : -INFINITY;
        m = fmaxf(m, v[nt]);
      }
#pragma unroll
      for (int off = 1; off < 16; off <<= 1) m = fmaxf(m, __shfl_xor(m, off));
      float es = 0.f;
#pragma unroll
      for (int nt = 0; nt < NT; ++nt)
        if ((nt * 16 + c) < DOUT) es += expf(v[nt] - m);
#pragma unroll
      for (int off = 1; off < 16; off <<= 1) es += __shfl_xor(es, off);
      float lse = logf(es);
      if (R < n) {
#pragma unroll
        for (int nt = 0; nt < NT; ++nt)
          if ((nt * 16 + c) < DOUT) out[(size_t)R * DOUT + nt * 16 + c] = v[nt] - m - lse;
      }
    }
  }
}

extern "C" void kernel_launch(void* const* d_in, const int* in_sizes, int n_in,
                              void* d_out, int out_size, void* d_ws, size_t ws_size,
                              hipStream_t stream) {
  const float* x   = (const float*)d_in[0];
  const int*   ei  = (const int*)d_in[1];
  const float* Wl0 = (const float*)d_in[2];
  const float* bl0 = (const float*)d_in[3];
  const float* Wr0 = (const float*)d_in[4];
  const float* Wl1 = (const float*)d_in[5];
  const float* bl1 = (const float*)d_in[6];
  const float* Wr1 = (const float*)d_in[7];
  const float* Wl2 = (const float*)d_in[8];
  const float* bl2 = (const float*)d_in[9];
  const float* Wr2 = (const float*)d_in[10];
  float* out = (float*)d_out;

  int N = in_sizes[0] / 64;
  int E = in_sizes[1] / 2;
  int M = N + 1;
  int NB = (N + 255) >> BSH;     // 391 for N=100000
  int NBLK = (E + 4095) / 4096;  // 391 for E=1.6M
  const int* src = ei;
  const int* dst = ei + E;

  char* p = (char*)d_ws;
  auto alloc = [&](size_t bytes) {
    char* r = p;
    p += (bytes + 255) & ~(size_t)255;
    return r;
  };
  int* cnt      = (int*)alloc((size_t)M * 4);
  int* row_ptr  = (int*)alloc((size_t)M * 4);
  int* cursor   = (int*)alloc((size_t)M * 4);
  int* bsum     = (int*)alloc(256 * 4);
  int* boff     = (int*)alloc(256 * 4);
  int* bk_cnt   = (int*)alloc((MAXNB + 1) * 4);
  int* bk_base  = (int*)alloc((MAXNB + 1) * 4);
  int* edge_src = (int*)alloc((size_t)E * 4);
  unsigned* tmp = (unsigned*)alloc((size_t)E * 4);          // packed (src<<8)|dst&255
  int* bk_blk   = (int*)alloc((size_t)MAXNB * (size_t)NBLK * 4);
  int* base_blk = (int*)alloc((size_t)MAXNB * (size_t)NBLK * 4);
  unsigned short* R1  = (unsigned short*)alloc((size_t)N * 128);  // xb, then hbB
  unsigned short* hbA = (unsigned short*)alloc((size_t)N * 128);  // hidden (bf16)
  unsigned short* Wb0 = (unsigned short*)alloc(128 * 64 * 2);
  unsigned short* Wb1 = (unsigned short*)alloc(128 * 64 * 2);
  unsigned short* Wb2 = (unsigned short*)alloc(128 * 48 * 2);
  if ((size_t)(p - (char*)d_ws) > ws_size) return;  // ws too small: fail loudly

  bool bucketed = (NB < MAXNB) && (N < (1 << 24)) && (NBLK <= 512);

  unsigned short* xb  = R1;
  unsigned short* hbB = R1;  // xb dead after layer 0

  // one-time weight pre-pack + bucket-count zero (single launch)
  k_prepw3<<<(22528 + 255) / 256, 256, 0, stream>>>(Wl0, Wr0, Wb0, Wl1, Wr1, Wb1,
                                                    Wl2, Wr2, Wb2, bk_cnt);

  if (bucketed) {
    // fused cast + bucket hist (+ per-block counts)
    k_histB<<<NBLK, 256, 0, stream>>>(dst, x, xb, bk_cnt, bk_blk, E, NB, NBLK, N * 8);
    k_bscan12<<<NB, 512, 0, stream>>>(bk_cnt, bk_blk, bk_base, base_blk, NB, NBLK);
    k_partition<<<NBLK, 256, 0, stream>>>(src, dst, base_blk, tmp, E, NB, NBLK);
    k_bmake<<<NB, 256, 0, stream>>>(tmp, bk_base, row_ptr, edge_src, N, E, NB);
  } else {
    k_zero<<<(M + 255) / 256, 256, 0, stream>>>(cnt, M);
    k_hist<<<(E + 255) / 256, 256, 0, stream>>>(dst, cnt, E);
    int nb = (M + 2047) / 2048;
    k_scan_part<<<nb, 256, 0, stream>>>(cnt, bsum, M);
    k_scan_mid<<<1, 64, 0, stream>>>(bsum, boff, nb);
    k_scan_final<<<nb, 256, 0, stream>>>(cnt, boff, row_ptr, cursor, M);
    k_fill<<<(E + 255) / 256, 256, 0, stream>>>(src, dst, cursor, edge_src, E);
    k_cast<<<(N * 8 + 255) / 256, 256, 0, stream>>>(x, xb, N * 64);
  }

  int gb = (N + 63) / 64;  // 4 waves/block x 16 rows/wave
  // layer 0: hbA = relu([mean_agg(xb), xb] @ [Wl0; Wr0] + bl0)
  k_layer<64, ACT_RELU><<<gb, 256, 0, stream>>>(xb, row_ptr, edge_src, Wb0, bl0, hbA, N);
  // layer 1: hbB = relu([mean_agg(hbA), hbA] @ [Wl1; Wr1] + bl1)
  k_layer<64, ACT_RELU><<<gb, 256, 0, stream>>>(hbA, row_ptr, edge_src, Wb1, bl1, hbB, N);
  // layer 2: out = log_softmax([mean_agg(hbB), hbB] @ [Wl2; Wr2] + bl2)
  k_layer<40, ACT_LSM><<<gb, 256, 0, stream>>>(hbB, row_ptr, edge_src, Wb2, bl2, out, N);
}

// Round 17
// 183.921 us; speedup vs baseline: 1.0593x; 1.0593x over previous
//
#include <hip/hip_runtime.h>
#include <math.h>

#define ACT_RELU 0
#define ACT_LSM  1
#define BSH 8        // bucket = 256 consecutive dst nodes
#define MAXNB 512    // max buckets supported by the scan / LDS hist
#define MPAD 80      // meanL row pad (ushorts)

typedef __attribute__((ext_vector_type(8))) short bf16x8;   // 8 bf16 (4 VGPRs)
typedef __attribute__((ext_vector_type(4))) float f32x4;

// bf16 helpers (OCP bf16 = top 16 bits of f32; RNE pack)
__device__ __forceinline__ unsigned f2bf(float f) {
  unsigned u = __float_as_uint(f);
  u += 0x7fffu + ((u >> 16) & 1u);
  return u >> 16;
}
__device__ __forceinline__ float bflo(unsigned u) { return __uint_as_float(u << 16); }
__device__ __forceinline__ float bfhi(unsigned u) { return __uint_as_float(u & 0xffff0000u); }

// ---------------- pre-pack ALL layer weights + zero bucket counts ----------------
__device__ __forceinline__ void prepw_one(const float* Wl, const float* Wr,
                                          unsigned short* Wb, int fi, int DOUT, int NT) {
  int k7 = fi & 7;
  int kb = (fi >> 3) & 3;
  int c16 = (fi >> 5) & 15;
  int rest = fi >> 9;
  int nt = rest % NT;
  int kb5 = rest / NT;
  int k = kb5 * 32 + kb * 8 + k7;
  int nn = nt * 16 + c16;
  float v = 0.f;
  if (nn < DOUT) v = (k < 64) ? Wl[k * DOUT + nn] : Wr[(k - 64) * DOUT + nn];
  Wb[fi] = (unsigned short)f2bf(v);
}

__global__ void k_prepw3(const float* __restrict__ Wl0, const float* __restrict__ Wr0,
                         unsigned short* __restrict__ Wb0,
                         const float* __restrict__ Wl1, const float* __restrict__ Wr1,
                         unsigned short* __restrict__ Wb1,
                         const float* __restrict__ Wl2, const float* __restrict__ Wr2,
                         unsigned short* __restrict__ Wb2,
                         int* __restrict__ bk_cnt) {
  int i = blockIdx.x * 256 + threadIdx.x;
  if (i < 8192) prepw_one(Wl0, Wr0, Wb0, i, 64, 4);
  else if (i < 16384) prepw_one(Wl1, Wr1, Wb1, i - 8192, 64, 4);
  else if (i < 22528) prepw_one(Wl2, Wr2, Wb2, i - 16384, 40, 3);
  if (i <= MAXNB) bk_cnt[i] = 0;  // fused zero of bucket counts
}

// ---------------- CSR build (bucketed, deterministic, atomic-light) ----------------
// Fused: grid-stride cast x->bf16 + per-4096-edge-chunk bucket histogram.
// Also stores per-(bucket,block) counts for the scan (no re-count in partition).
__global__ void __launch_bounds__(256) k_histB(const int* __restrict__ dst,
                                               const float* __restrict__ x,
                                               unsigned short* __restrict__ xb,
                                               int* __restrict__ bucket_cnt,
                                               int* __restrict__ bk_blk,  // [b*NBLK+blk]
                                               int E, int NB, int NBLK, int nx8) {
  __shared__ int cntL[MAXNB];
  int t = threadIdx.x;
  // ---- fused cast (grid-stride, independent of hist) ----
  for (int i = blockIdx.x * 256 + t; i < nx8; i += gridDim.x * 256) {
    const float4* p = (const float4*)(x + (size_t)i * 8);
    float4 a = p[0], b = p[1];
    uint4 w;
    w.x = f2bf(a.x) | (f2bf(a.y) << 16);
    w.y = f2bf(a.z) | (f2bf(a.w) << 16);
    w.z = f2bf(b.x) | (f2bf(b.y) << 16);
    w.w = f2bf(b.z) | (f2bf(b.w) << 16);
    *(uint4*)(xb + (size_t)i * 8) = w;
  }
  // ---- bucket histogram for this block's edge chunk ----
  for (int b = t; b < NB; b += 256) cntL[b] = 0;
  __syncthreads();
  int e0 = blockIdx.x * 4096;
  int e1 = min(e0 + 4096, E);
  for (int i = e0 + t; i < e1; i += 256) atomicAdd(&cntL[dst[i] >> BSH], 1);
  __syncthreads();
  for (int b = t; b < NB; b += 256) {
    int c = cntL[b];
    bk_blk[b * NBLK + blockIdx.x] = c;
    if (c) atomicAdd(&bucket_cnt[b], c);
  }
}

__global__ void k_bscan(const int* __restrict__ bucket_cnt, int* __restrict__ bucket_base,
                        int NB) {
  __shared__ int sm[MAXNB];
  int t = threadIdx.x;  // 512 threads
  sm[t] = (t < NB) ? bucket_cnt[t] : 0;
  __syncthreads();
  for (int off = 1; off < MAXNB; off <<= 1) {
    int x = (t >= off) ? sm[t - off] : 0;
    __syncthreads();
    sm[t] += x;
    __syncthreads();
  }
  int ex = (t == 0) ? 0 : sm[t - 1];
  if (t <= NB) bucket_base[t] = ex;
}

// per-(bucket,block) exclusive bases: base_blk[b][blk] = bk_base[b] + prefix(bk_blk[b][<blk])
__global__ void k_bscan2(const int* __restrict__ bk_blk, const int* __restrict__ bucket_base,
                         int* __restrict__ base_blk, int NBLK) {
  __shared__ int sm[512];
  int b = blockIdx.x;
  int t = threadIdx.x;  // 512 threads, NBLK <= 512
  int v = (t < NBLK) ? bk_blk[b * NBLK + t] : 0;
  sm[t] = v;
  __syncthreads();
  for (int off = 1; off < 512; off <<= 1) {
    int x = (t >= off) ? sm[t - off] : 0;
    __syncthreads();
    sm[t] += x;
    __syncthreads();
  }
  if (t < NBLK) base_blk[b * NBLK + t] = bucket_base[b] + sm[t] - v;
}

// single-pass partition: per-block bases precomputed; tmp packed 4B (src<<8)|(dst&255)
__global__ void k_partition(const int* __restrict__ src, const int* __restrict__ dst,
                            const int* __restrict__ base_blk, unsigned* __restrict__ tmp,
                            int E, int NB, int NBLK) {
  __shared__ int curL[MAXNB];
  int t = threadIdx.x;
  for (int b = t; b < NB; b += 256) curL[b] = base_blk[b * NBLK + blockIdx.x];
  __syncthreads();
  int e0 = blockIdx.x * 4096;
  int e1 = min(e0 + 4096, E);
  for (int i = e0 + t; i < e1; i += 256) {
    int s = src[i], d = dst[i];
    int b = d >> BSH;
    int r = atomicAdd(&curL[b], 1);  // LDS atomic
    tmp[r] = ((unsigned)s << 8) | (unsigned)(d & 255);
  }
}

__global__ void __launch_bounds__(256) k_bmake(const unsigned* __restrict__ tmp,
                                               const int* __restrict__ bucket_base,
                                               int* __restrict__ row_ptr,
                                               int* __restrict__ edge_src,
                                               int N, int E, int NB) {
  __shared__ int cntL[256];
  __shared__ int scanL[256];
  int b = blockIdx.x;
  int t = threadIdx.x;
  int e0 = bucket_base[b], e1 = bucket_base[b + 1];
  cntL[t] = 0;
  __syncthreads();
  for (int i = e0 + t; i < e1; i += 256) atomicAdd(&cntL[tmp[i] & 255], 1);
  __syncthreads();
  int v = cntL[t];
  scanL[t] = v;
  __syncthreads();
  for (int off = 1; off < 256; off <<= 1) {
    int x = (t >= off) ? scanL[t - off] : 0;
    __syncthreads();
    scanL[t] += x;
    __syncthreads();
  }
  int exc = scanL[t] - v;
  int node = (b << BSH) + t;
  if (node < N) row_ptr[node] = e0 + exc;
  if (b == NB - 1 && t == 0) row_ptr[N] = E;
  __syncthreads();
  cntL[t] = e0 + exc;  // reuse as cursor
  __syncthreads();
  for (int i = e0 + t; i < e1; i += 256) {
    unsigned e = tmp[i];
    int p = atomicAdd(&cntL[e & 255], 1);  // LDS atomic
    edge_src[p] = (int)(e >> 8);
  }
}

// ---------------- fallback path (NB > MAXNB or N >= 2^24 or NBLK > 512) ----------------
__global__ void k_zero(int* __restrict__ p, int n) {
  int i = blockIdx.x * 256 + threadIdx.x;
  if (i < n) p[i] = 0;
}

__global__ void k_hist(const int* __restrict__ dst, int* __restrict__ cnt, int E) {
  int i = blockIdx.x * blockDim.x + threadIdx.x;
  if (i < E) atomicAdd(&cnt[dst[i]], 1);
}

__global__ void k_scan_part(const int* __restrict__ cnt, int* __restrict__ bsum, int M) {
  __shared__ int sm[256];
  int t = threadIdx.x;
  int base = blockIdx.x * 2048 + t * 8;
  int s = 0;
#pragma unroll
  for (int j = 0; j < 8; ++j) { int i = base + j; if (i < M) s += cnt[i]; }
  sm[t] = s;
  __syncthreads();
  for (int off = 128; off > 0; off >>= 1) {
    if (t < off) sm[t] += sm[t + off];
    __syncthreads();
  }
  if (t == 0) bsum[blockIdx.x] = sm[0];
}

__global__ void k_scan_mid(const int* __restrict__ bsum, int* __restrict__ boff, int nb) {
  int l = threadIdx.x;
  int v = (l < nb) ? bsum[l] : 0;
  int inc = v;
  for (int off = 1; off < 64; off <<= 1) {
    int u = __shfl_up(inc, off);
    if (l >= off) inc += u;
  }
  if (l < nb) boff[l] = inc - v;
}

__global__ void k_scan_final(const int* __restrict__ cnt, const int* __restrict__ boff,
                             int* __restrict__ row_ptr, int* __restrict__ cursor, int M) {
  __shared__ int sm[256];
  int t = threadIdx.x;
  int base = blockIdx.x * 2048 + t * 8;
  int v[8];
  int s = 0;
#pragma unroll
  for (int j = 0; j < 8; ++j) { int i = base + j; v[j] = (i < M) ? cnt[i] : 0; s += v[j]; }
  sm[t] = s;
  __syncthreads();
  for (int off = 1; off < 256; off <<= 1) {
    int x = (t >= off) ? sm[t - off] : 0;
    __syncthreads();
    sm[t] += x;
    __syncthreads();
  }
  int run = boff[blockIdx.x] + sm[t] - s;
#pragma unroll
  for (int j = 0; j < 8; ++j) {
    int i = base + j;
    if (i < M) { row_ptr[i] = run; cursor[i] = run; }
    run += v[j];
  }
}

__global__ void k_fill(const int* __restrict__ src, const int* __restrict__ dst,
                       int* __restrict__ cursor, int* __restrict__ edge_src, int E) {
  int i = blockIdx.x * blockDim.x + threadIdx.x;
  if (i < E) {
    int d = dst[i];
    int p = atomicAdd(&cursor[d], 1);
    edge_src[p] = src[i];
  }
}

__global__ void __launch_bounds__(256) k_cast(const float* __restrict__ x,
                                              unsigned short* __restrict__ xb, int n) {
  int i = blockIdx.x * 256 + threadIdx.x;  // unit of 8 elements
  if (i * 8 < n) {
    const float4* p = (const float4*)(x + (size_t)i * 8);
    float4 a = p[0], b = p[1];
    uint4 w;
    w.x = f2bf(a.x) | (f2bf(a.y) << 16);
    w.y = f2bf(a.z) | (f2bf(a.w) << 16);
    w.z = f2bf(b.x) | (f2bf(b.y) << 16);
    w.w = f2bf(b.z) | (f2bf(b.w) << 16);
    *(uint4*)(xb + (size_t)i * 8) = w;
  }
}

// ---------------- fused SAGE layer: out = act([mean_agg(h), h] @ [Wl; Wr] + b) ----------------
// R13-proven structure: 4 waves/block, 16 rows/wave, wave-private meanL (no
// block barrier), W fragments from global (pre-packed), LDS 10.2KB.
// Phase A: gather-mean (8 lanes/node, 8 edges in flight, guarded loads -> VGPR 44).
// Phase B: MFMA K=128.
// mfma_f32_16x16x32_bf16: A row = lane&15, k = (lane>>4)*8+j; C/D col = lane&15,
// row = (lane>>4)*4 + reg  [verified R6-R16].
template <int DOUT, int ACT>
__global__ void __launch_bounds__(256) k_layer(const unsigned short* __restrict__ h,
                                               const int* __restrict__ row_ptr,
                                               const int* __restrict__ edge_src,
                                               const unsigned short* __restrict__ Wb,
                                               const float* __restrict__ bias,
                                               void* __restrict__ outv, int n) {
  constexpr int NT = (DOUT + 15) / 16;  // 4 (d=64) or 3 (d=40)
  __shared__ unsigned short meanL[4][16 * MPAD];
  int t = threadIdx.x;
  int w = t >> 6, lane = t & 63;
  int r0 = (blockIdx.x * 4 + w) * 16;  // wave's 16 rows
  int g = lane & 7;                    // dim-group of 8 bf16 (16B)

  // ---- phase A: gather-mean, two batches of 8 nodes, 8 edges in flight ----
  for (int half = 0; half < 2; ++half) {
    int node = half * 8 + (lane >> 3);
    int i = r0 + node;
    float a[8];
#pragma unroll
    for (int c = 0; c < 8; ++c) a[c] = 0.f;
    float scale = 0.f;
    if (i < n) {
      int rp0 = row_ptr[i], rp1 = row_ptr[i + 1];
      int deg = rp1 - rp0;
      scale = (deg > 0) ? (1.0f / (float)deg) : 0.f;
      for (int base = 0; base < deg; base += 8) {
        int idx = rp0 + base + g;
        int sv = (idx < rp1) ? edge_src[idx] : 0;  // 8 edges per node, coalesced
        int cnt = min(8, deg - base);
        uint4 v0, v1, v2, v3, v4, v5, v6, v7;
#pragma unroll
        for (int e = 0; e < 8; ++e) {
          int s = __shfl(sv, (lane & ~7) | e);
          const uint4* p = (const uint4*)(h + (size_t)s * 64) + g;
          if (e == 0 && e < cnt) v0 = *p;
          if (e == 1 && e < cnt) v1 = *p;
          if (e == 2 && e < cnt) v2 = *p;
          if (e == 3 && e < cnt) v3 = *p;
          if (e == 4 && e < cnt) v4 = *p;
          if (e == 5 && e < cnt) v5 = *p;
          if (e == 6 && e < cnt) v6 = *p;
          if (e == 7 && e < cnt) v7 = *p;
        }
#define ACCUM(vv, ee)                                                   \
        if ((ee) < cnt) {                                               \
          a[0] += bflo(vv.x); a[1] += bfhi(vv.x);                       \
          a[2] += bflo(vv.y); a[3] += bfhi(vv.y);                       \
          a[4] += bflo(vv.z); a[5] += bfhi(vv.z);                       \
          a[6] += bflo(vv.w); a[7] += bfhi(vv.w);                       \
        }
        ACCUM(v0, 0) ACCUM(v1, 1) ACCUM(v2, 2) ACCUM(v3, 3)
        ACCUM(v4, 4) ACCUM(v5, 5) ACCUM(v6, 6) ACCUM(v7, 7)
#undef ACCUM
      }
    }
    uint4 wv;
    wv.x = f2bf(a[0] * scale) | (f2bf(a[1] * scale) << 16);
    wv.y = f2bf(a[2] * scale) | (f2bf(a[3] * scale) << 16);
    wv.z = f2bf(a[4] * scale) | (f2bf(a[5] * scale) << 16);
    wv.w = f2bf(a[6] * scale) | (f2bf(a[7] * scale) << 16);
    *(uint4*)&meanL[w][node * MPAD + g * 8] = wv;
  }
  // meanL is wave-private: LDS fence only, no block barrier.
  __threadfence_block();

  // ---- phase B: MFMA ----
  int c = lane & 15;   // A row / C-D col
  int kb = lane >> 4;  // k-block of 8
  bf16x8 af[4];
  af[0] = *(const bf16x8*)&meanL[w][c * MPAD + kb * 8];        // mean, k 0..31
  af[1] = *(const bf16x8*)&meanL[w][c * MPAD + 32 + kb * 8];   // mean, k 32..63
  int row = r0 + c;
  if (row >= n) row = n - 1;  // clamp loads; stores guarded
  size_t rb = (size_t)row * 64 + kb * 8;
  af[2] = *(const bf16x8*)(h + rb);        // own row, k 0..31
  af[3] = *(const bf16x8*)(h + rb + 32);   // own row, k 32..63

  f32x4 acc[NT];
#pragma unroll
  for (int nt = 0; nt < NT; ++nt) acc[nt] = (f32x4){0.f, 0.f, 0.f, 0.f};
#pragma unroll
  for (int s = 0; s < 4; ++s) {
    bf16x8 bft[NT];  // load W frags per-s to cap register liveness
#pragma unroll
    for (int nt = 0; nt < NT; ++nt)
      bft[nt] = *(const bf16x8*)&Wb[(((s * NT + nt) * 16 + c) * 4 + kb) * 8];
#pragma unroll
    for (int nt = 0; nt < NT; ++nt)
      acc[nt] = __builtin_amdgcn_mfma_f32_16x16x32_bf16(af[s], bft[nt], acc[nt], 0, 0, 0);
  }

  int rbase = r0 + kb * 4;
  if (ACT == ACT_RELU) {
    unsigned short* out = (unsigned short*)outv;
#pragma unroll
    for (int nt = 0; nt < NT; ++nt) {
      float bval = bias[nt * 16 + c];
#pragma unroll
      for (int r = 0; r < 4; ++r) {
        int R = rbase + r;
        if (R < n) {
          float v = fmaxf(acc[nt][r] + bval, 0.f);
          out[(size_t)R * DOUT + nt * 16 + c] = (unsigned short)f2bf(v);
        }
      }
    }
  } else {
    float* out = (float*)outv;
    float bv[NT];
#pragma unroll
    for (int nt = 0; nt < NT; ++nt) bv[nt] = ((nt * 16 + c) < DOUT) ? bias[nt * 16 + c] : 0.f;
#pragma unroll
    for (int r = 0; r < 4; ++r) {
      int R = rbase + r;
      float v[NT];
      float m = -INFINITY;
#pragma unroll
      for (int nt = 0; nt < NT; ++nt) {
        bool valid = (nt * 16 + c) < DOUT;
        v[nt] = valid ? (acc[nt][r] + bv[nt]) : -INFINITY;
        m = fmaxf(m, v[nt]);
      }
#pragma unroll
      for (int off = 1; off < 16; off <<= 1) m = fmaxf(m, __shfl_xor(m, off));
      float es = 0.f;
#pragma unroll
      for (int nt = 0; nt < NT; ++nt)
        if ((nt * 16 + c) < DOUT) es += expf(v[nt] - m);
#pragma unroll
      for (int off = 1; off < 16; off <<= 1) es += __shfl_xor(es, off);
      float lse = logf(es);
      if (R < n) {
#pragma unroll
        for (int nt = 0; nt < NT; ++nt)
          if ((nt * 16 + c) < DOUT) out[(size_t)R * DOUT + nt * 16 + c] = v[nt] - m - lse;
      }
    }
  }
}

extern "C" void kernel_launch(void* const* d_in, const int* in_sizes, int n_in,
                              void* d_out, int out_size, void* d_ws, size_t ws_size,
                              hipStream_t stream) {
  const float* x   = (const float*)d_in[0];
  const int*   ei  = (const int*)d_in[1];
  const float* Wl0 = (const float*)d_in[2];
  const float* bl0 = (const float*)d_in[3];
  const float* Wr0 = (const float*)d_in[4];
  const float* Wl1 = (const float*)d_in[5];
  const float* bl1 = (const float*)d_in[6];
  const float* Wr1 = (const float*)d_in[7];
  const float* Wl2 = (const float*)d_in[8];
  const float* bl2 = (const float*)d_in[9];
  const float* Wr2 = (const float*)d_in[10];
  float* out = (float*)d_out;

  int N = in_sizes[0] / 64;
  int E = in_sizes[1] / 2;
  int M = N + 1;
  int NB = (N + 255) >> BSH;     // 391 for N=100000
  int NBLK = (E + 4095) / 4096;  // 391 for E=1.6M
  const int* src = ei;
  const int* dst = ei + E;

  char* p = (char*)d_ws;
  auto alloc = [&](size_t bytes) {
    char* r = p;
    p += (bytes + 255) & ~(size_t)255;
    return r;
  };
  int* cnt      = (int*)alloc((size_t)M * 4);
  int* row_ptr  = (int*)alloc((size_t)M * 4);
  int* cursor   = (int*)alloc((size_t)M * 4);
  int* bsum     = (int*)alloc(256 * 4);
  int* boff     = (int*)alloc(256 * 4);
  int* bk_cnt   = (int*)alloc((MAXNB + 1) * 4);
  int* bk_base  = (int*)alloc((MAXNB + 1) * 4);
  int* edge_src = (int*)alloc((size_t)E * 4);
  unsigned* tmp = (unsigned*)alloc((size_t)E * 4);          // packed (src<<8)|dst&255
  int* bk_blk   = (int*)alloc((size_t)MAXNB * (size_t)NBLK * 4);
  int* base_blk = (int*)alloc((size_t)MAXNB * (size_t)NBLK * 4);
  unsigned short* R1  = (unsigned short*)alloc((size_t)N * 128);  // xb, then hbB
  unsigned short* hbA = (unsigned short*)alloc((size_t)N * 128);  // hidden (bf16)
  unsigned short* Wb0 = (unsigned short*)alloc(128 * 64 * 2);
  unsigned short* Wb1 = (unsigned short*)alloc(128 * 64 * 2);
  unsigned short* Wb2 = (unsigned short*)alloc(128 * 48 * 2);
  if ((size_t)(p - (char*)d_ws) > ws_size) return;  // ws too small: fail loudly

  bool bucketed = (NB <= MAXNB) && (N < (1 << 24)) && (NBLK <= 512);

  unsigned short* xb  = R1;
  unsigned short* hbB = R1;  // xb dead after layer 0

  // one-time weight pre-pack + bucket-count zero (single launch)
  k_prepw3<<<(22528 + 255) / 256, 256, 0, stream>>>(Wl0, Wr0, Wb0, Wl1, Wr1, Wb1,
                                                    Wl2, Wr2, Wb2, bk_cnt);

  if (bucketed) {
    // fused cast + bucket hist (+ per-block counts)
    k_histB<<<NBLK, 256, 0, stream>>>(dst, x, xb, bk_cnt, bk_blk, E, NB, NBLK, N * 8);
    k_bscan<<<1, MAXNB, 0, stream>>>(bk_cnt, bk_base, NB);
    k_bscan2<<<NB, 512, 0, stream>>>(bk_blk, bk_base, base_blk, NBLK);
    k_partition<<<NBLK, 256, 0, stream>>>(src, dst, base_blk, tmp, E, NB, NBLK);
    k_bmake<<<NB, 256, 0, stream>>>(tmp, bk_base, row_ptr, edge_src, N, E, NB);
  } else {
    k_zero<<<(M + 255) / 256, 256, 0, stream>>>(cnt, M);
    k_hist<<<(E + 255) / 256, 256, 0, stream>>>(dst, cnt, E);
    int nb = (M + 2047) / 2048;
    k_scan_part<<<nb, 256, 0, stream>>>(cnt, bsum, M);
    k_scan_mid<<<1, 64, 0, stream>>>(bsum, boff, nb);
    k_scan_final<<<nb, 256, 0, stream>>>(cnt, boff, row_ptr, cursor, M);
    k_fill<<<(E + 255) / 256, 256, 0, stream>>>(src, dst, cursor, edge_src, E);
    k_cast<<<(N * 8 + 255) / 256, 256, 0, stream>>>(x, xb, N * 64);
  }

  int gb = (N + 63) / 64;  // 4 waves/block x 16 rows/wave
  // layer 0: hbA = relu([mean_agg(xb), xb] @ [Wl0; Wr0] + bl0)
  k_layer<64, ACT_RELU><<<gb, 256, 0, stream>>>(xb, row_ptr, edge_src, Wb0, bl0, hbA, N);
  // layer 1: hbB = relu([mean_agg(hbA), hbA] @ [Wl1; Wr1] + bl1)
  k_layer<64, ACT_RELU><<<gb, 256, 0, stream>>>(hbA, row_ptr, edge_src, Wb1, bl1, hbB, N);
  // layer 2: out = log_softmax([mean_agg(hbB), hbB] @ [Wl2; Wr2] + bl2)
  k_layer<40, ACT_LSM><<<gb, 256, 0, stream>>>(hbB, row_ptr, edge_src, Wb2, bl2, out, N);
}